// Round 7
// baseline (882.251 us; speedup 1.0000x reference)
//
#include <hip/hip_runtime.h>

typedef __attribute__((ext_vector_type(4))) float f32x4;
typedef __attribute__((ext_vector_type(8))) __bf16 bf16x8;
typedef __attribute__((ext_vector_type(2))) __bf16 bf16x2;
typedef __attribute__((ext_vector_type(8))) unsigned short u16x8;
typedef __attribute__((ext_vector_type(2))) unsigned int u32x2;

#define MFMA16(a, b, c) \
  __builtin_amdgcn_mfma_f32_16x16x32_bf16(__builtin_bit_cast(bf16x8, (a)), \
                                          __builtin_bit_cast(bf16x8, (b)), (c), 0, 0, 0)

__device__ __forceinline__ unsigned short f2bf(float f) {
  unsigned int u = __builtin_bit_cast(unsigned int, f);
  u += 0x7FFFu + ((u >> 16) & 1u);   // RNE; inputs are finite
  return (unsigned short)(u >> 16);
}

// native casts -> compiler emits v_cvt_pk_bf16_f32
__device__ __forceinline__ unsigned int packbf2(float lo, float hi) {
  bf16x2 v;
  v[0] = (__bf16)lo;
  v[1] = (__bf16)hi;
  return __builtin_bit_cast(unsigned int, v);
}

// async global -> LDS, 16B per lane. Dest must be linear: HW writes
// wave-uniform-base + lane*16 (m104/m108).
__device__ __forceinline__ void gload16(const void* g, void* l) {
  __builtin_amdgcn_global_load_lds(
      (const __attribute__((address_space(1))) void*)g,
      (__attribute__((address_space(3))) void*)l, 16, 0, 0);
}

// ---------------------------------------------------------------------------
// Kernel 0: X fp32 -> bf16. grid 8192, block 256.
// ---------------------------------------------------------------------------
__global__ __launch_bounds__(256) void xconv(
    const float* __restrict__ X, unsigned short* __restrict__ Xb)
{
  size_t i = ((size_t)blockIdx.x * 256 + threadIdx.x) * 8;
  f32x4 f0 = *(const f32x4*)(X + i);
  f32x4 f1 = *(const f32x4*)(X + i + 4);
  u16x8 v;
  v[0] = f2bf(f0[0]); v[1] = f2bf(f0[1]); v[2] = f2bf(f0[2]); v[3] = f2bf(f0[3]);
  v[4] = f2bf(f1[0]); v[5] = f2bf(f1[1]); v[6] = f2bf(f1[2]); v[7] = f2bf(f1[3]);
  *(u16x8*)(Xb + i) = v;
}

// ---------------------------------------------------------------------------
// Kernel 1: transpose + fp32->bf16 convert the four weight matrices.
// Wt[z][n][k] = W_z[k][n]. grid (32,32,4), block (32,8)
// ---------------------------------------------------------------------------
__global__ __launch_bounds__(256) void wtrans(
    const float* __restrict__ Wq, const float* __restrict__ Wk,
    const float* __restrict__ Wv, const float* __restrict__ Wo,
    unsigned short* __restrict__ Wt)
{
  __shared__ unsigned short tile[32][33];
  const int z = blockIdx.z;
  const float* W = (z == 0) ? Wq : (z == 1) ? Wk : (z == 2) ? Wv : Wo;
  unsigned short* T = Wt + (size_t)z * 1024 * 1024;
  const int tx = threadIdx.x, ty = threadIdx.y;
  const int x = blockIdx.x * 32 + tx;
  const int y0 = blockIdx.y * 32;
#pragma unroll
  for (int i = 0; i < 4; ++i)
    tile[ty + i * 8][tx] = f2bf(W[(size_t)(y0 + ty + i * 8) * 1024 + x]);
  __syncthreads();
#pragma unroll
  for (int i = 0; i < 4; ++i)
    T[(size_t)(blockIdx.x * 32 + ty + i * 8) * 1024 + y0 + tx] = tile[tx][ty + i * 8];
}

// ---------------------------------------------------------------------------
// Kernel 2: QKV projection GEMM, global_load_lds staging (proven round 5).
// grid (24, 128), block 256.
// ---------------------------------------------------------------------------
__global__ __launch_bounds__(256) void qkv_gemm(
    const unsigned short* __restrict__ Xb, const unsigned short* __restrict__ Wt,
    unsigned short* __restrict__ Qo, unsigned short* __restrict__ Ko,
    unsigned short* __restrict__ Vo)
{
  const int bx = blockIdx.x;
  const int z = bx >> 3;
  const int bn = (bx & 7) * 128;
  const int bm = blockIdx.y * 128;
  const unsigned short* Wz = Wt + (size_t)z * 1024 * 1024;
  unsigned short* Out = (z == 0) ? Qo : (z == 1) ? Ko : Vo;

  const int tid = threadIdx.x;
  const int w = tid >> 6, l = tid & 63, l15 = l & 15, lg = l >> 4;
  const int wr = w >> 1, wc = w & 1;

  __shared__ alignas(16) unsigned short sA[128][32];
  __shared__ alignas(16) unsigned short sB[128][32];

  const int srow = w * 32 + (l >> 2);
  const int scol = (l & 3) * 8;
  const unsigned short* gA = Xb + (size_t)(bm + srow) * 1024 + scol;
  const unsigned short* gB = Wz + (size_t)(bn + srow) * 1024 + scol;
  unsigned short* lA = &sA[srow][scol];
  unsigned short* lB = &sB[srow][scol];

  f32x4 acc[4][4];
  const f32x4 zero = {0.f, 0.f, 0.f, 0.f};
#pragma unroll
  for (int i = 0; i < 4; ++i)
#pragma unroll
    for (int j = 0; j < 4; ++j) acc[i][j] = zero;

  for (int k0 = 0; k0 < 1024; k0 += 32) {
    __syncthreads();
#pragma unroll
    for (int p = 0; p < 2; ++p) {
      gload16(gA + (size_t)p * 16 * 1024 + k0, lA + p * 16 * 32);
      gload16(gB + (size_t)p * 16 * 1024 + k0, lB + p * 16 * 32);
    }
    __syncthreads();

    u16x8 af[4], bf[4];
#pragma unroll
    for (int m = 0; m < 4; ++m)
      af[m] = *(const u16x8*)&sA[wr * 64 + m * 16 + l15][lg * 8];
#pragma unroll
    for (int n = 0; n < 4; ++n)
      bf[n] = *(const u16x8*)&sB[wc * 64 + n * 16 + l15][lg * 8];
#pragma unroll
    for (int m = 0; m < 4; ++m)
#pragma unroll
      for (int n = 0; n < 4; ++n)
        acc[m][n] = MFMA16(af[m], bf[n], acc[m][n]);
  }

#pragma unroll
  for (int m = 0; m < 4; ++m) {
    int grow_b = bm + wr * 64 + m * 16 + lg * 4;
#pragma unroll
    for (int n = 0; n < 4; ++n) {
      int gcol = bn + wc * 64 + n * 16 + l15;
      int hh = gcol >> 6, dk = gcol & 63;
#pragma unroll
      for (int t = 0; t < 4; ++t) {
        int grow = grow_b + t;
        int bb = grow >> 10, s = grow & 1023;
        Out[(((size_t)(bb * 16 + hh)) * 1024 + s) * 64 + dk] = f2bf(acc[m][n][t]);
      }
    }
  }
}

// ---------------------------------------------------------------------------
// Kernel 2b: V -> V^T per (b,h): Vt[b][h][d][s] = V[b][h][s][d].
// grid (16, 256), block 256
// ---------------------------------------------------------------------------
__global__ __launch_bounds__(256) void vtrans(
    const unsigned short* __restrict__ V, unsigned short* __restrict__ Vt)
{
  __shared__ unsigned short tile[64 * 64];
  const int s0 = blockIdx.x * 64;
  const size_t bh = (size_t)blockIdx.y * (64 * 1024);
  const int tid = threadIdx.x;

#pragma unroll
  for (int p = 0; p < 2; ++p) {
    int id = p * 256 + tid;
    int s = id >> 3, cc = id & 7;
    u16x8 v = *(const u16x8*)(V + bh + (size_t)(s0 + s) * 64 + cc * 8);
    *(u16x8*)&tile[s * 64 + ((cc ^ (s >> 3)) * 8)] = v;
  }
  __syncthreads();
#pragma unroll
  for (int p = 0; p < 2; ++p) {
    int id = p * 256 + tid;
    int d = id >> 3, sc = id & 7;
    u16x8 v;
#pragma unroll
    for (int i = 0; i < 8; ++i)
      v[i] = tile[(sc * 8 + i) * 64 + (((d >> 3) ^ sc) * 8) + (d & 7)];
    *(u16x8*)(Vt + bh + (size_t)d * 1024 + s0 + sc * 8) = v;
  }
}

// ---------------------------------------------------------------------------
// Kernel 3: fused attention, swapped-operand, barrier-free.
// K/Vt fragments read DIRECTLY from global (L1/L2-resident at S=1024;
// staging was pure overhead). Only LDS use is per-wave sP -> no
// __syncthreads at all. Native cvt_pk packing, exp2-folded softmax,
// defer-max (THR=8). grid (16, 16, 16) = (qtile, h, b), block 256.
// ---------------------------------------------------------------------------
__global__ __launch_bounds__(256) void attn(
    const unsigned short* __restrict__ Q, const unsigned short* __restrict__ Kg,
    const unsigned short* __restrict__ Vtg, const float* __restrict__ LL,
    const float* __restrict__ btr, unsigned short* __restrict__ O)
{
  const int q0 = blockIdx.x * 64;
  const int h = blockIdx.y, b = blockIdx.z;
  const int tid = threadIdx.x;
  const int w = tid >> 6, l = tid & 63, l15 = l & 15, lg = l >> 4;

  __shared__ alignas(16) unsigned short sP[4][16 * 64];

  const float bt = btr[h];
  const size_t bh = (size_t)(b * 16 + h) * (1024 * 64);

  // Q fragment (B-operand of swapped QK^T): col = qrow = l15, k = d
  u16x8 qf[2];
  {
    const unsigned short* qp = Q + bh + (size_t)(q0 + w * 16 + l15) * 64 + lg * 8;
    qf[0] = *(const u16x8*)qp;
    qf[1] = *(const u16x8*)(qp + 32);
  }
  const int qrow = q0 + w * 16 + l15;

  // direct-from-global fragment pointers (advance per K-tile)
  const unsigned short* kA[4];   // K[kt*64 + jn*16 + l15][dc*32 + lg*8]
#pragma unroll
  for (int jn = 0; jn < 4; ++jn)
    kA[jn] = Kg + bh + (size_t)(jn * 16 + l15) * 64 + lg * 8;
  const unsigned short* vA[4];   // Vt[dn*16 + l15][kt*64 + kc*32 + lg*8]
#pragma unroll
  for (int dn = 0; dn < 4; ++dn)
    vA[dn] = Vtg + bh + (size_t)(dn * 16 + l15) * 1024 + lg * 8;

  // hoisted sP offsets (kt-invariant)
  unsigned short* sPw = &sP[w][0];
  int wr_off[4];
#pragma unroll
  for (int jn = 0; jn < 4; ++jn)
    wr_off[jn] = l15 * 64 + (((jn * 2 + (lg >> 1)) ^ (l15 & 7)) * 8) + (lg & 1) * 4;
  int rd_off[2];
#pragma unroll
  for (int kc = 0; kc < 2; ++kc)
    rd_off[kc] = l15 * 64 + (((kc * 4 + lg) ^ (l15 & 7)) * 8);

  const float* llp = LL + (size_t)qrow * 1024 + lg * 4;

  float mrow = -3e38f, lrow = 0.f;
  f32x4 o[4];
  const f32x4 zero = {0.f, 0.f, 0.f, 0.f};
#pragma unroll
  for (int dn = 0; dn < 4; ++dn) o[dn] = zero;

  const float L2E = 1.44269504f;

  for (int kt = 0; kt < 16; ++kt) {
    // scores: St = K @ Q^T -> s4[jn][t] for qrow=l15, kpos=kt*64+jn*16+lg*4+t
    f32x4 s4[4];
#pragma unroll
    for (int jn = 0; jn < 4; ++jn) s4[jn] = zero;
#pragma unroll
    for (int dc = 0; dc < 2; ++dc) {
#pragma unroll
      for (int jn = 0; jn < 4; ++jn) {
        u16x8 kfr = *(const u16x8*)(kA[jn] + dc * 32);
        s4[jn] = MFMA16(kfr, qf[dc], s4[jn]);
      }
    }
#pragma unroll
    for (int jn = 0; jn < 4; ++jn) kA[jn] += 64 * 64;

    // scale + per-head-scaled lead-lag bias (vector f32x4 -> pk ops)
#pragma unroll
    for (int jn = 0; jn < 4; ++jn) {
      f32x4 llv = *(const f32x4*)(llp + jn * 16);
      s4[jn] = s4[jn] * 0.125f + bt * llv;
    }
    llp += 64;

    // row max (row = lanes (l15, lg=0..3) x 16 regs)
    float tm = fmaxf(fmaxf(s4[0][0], s4[0][1]), fmaxf(s4[0][2], s4[0][3]));
#pragma unroll
    for (int jn = 1; jn < 4; ++jn)
      tm = fmaxf(tm, fmaxf(fmaxf(s4[jn][0], s4[jn][1]), fmaxf(s4[jn][2], s4[jn][3])));
    tm = fmaxf(tm, __shfl_xor(tm, 16, 64));
    tm = fmaxf(tm, __shfl_xor(tm, 32, 64));

    // defer-max: only rescale when max grew by > 8
    if (__any(tm > mrow + 8.f)) {
      float mn = fmaxf(mrow, tm);
      float sc = __expf(mrow - mn);
      mrow = mn;
      lrow *= sc;
#pragma unroll
      for (int dn = 0; dn < 4; ++dn) o[dn] *= sc;
    }

    // p = exp2(s*log2e - m*log2e): 1 fma + 1 v_exp per score
    const float mnl = mrow * L2E;
    f32x4 pv4[4];
#pragma unroll
    for (int jn = 0; jn < 4; ++jn)
#pragma unroll
      for (int t = 0; t < 4; ++t)
        pv4[jn][t] = exp2f(s4[jn][t] * L2E - mnl);

    f32x4 a4 = (pv4[0] + pv4[1]) + (pv4[2] + pv4[3]);
    float rs = (a4[0] + a4[1]) + (a4[2] + a4[3]);
    rs += __shfl_xor(rs, 16, 64);
    rs += __shfl_xor(rs, 32, 64);
    lrow += rs;

    // P -> per-wave LDS (native cvt_pk packs, b64 writes)
#pragma unroll
    for (int jn = 0; jn < 4; ++jn) {
      u32x2 v2;
      v2[0] = packbf2(pv4[jn][0], pv4[jn][1]);
      v2[1] = packbf2(pv4[jn][2], pv4[jn][3]);
      *(u32x2*)&sPw[wr_off[jn]] = v2;
    }

    // PV: O^T += Vt @ P^T (A = Vt frag direct from global, B = P frag)
#pragma unroll
    for (int kc = 0; kc < 2; ++kc) {
      u16x8 pb = *(const u16x8*)&sPw[rd_off[kc]];
#pragma unroll
      for (int dn = 0; dn < 4; ++dn) {
        u16x8 vfr = *(const u16x8*)(vA[dn] + kc * 32);
        o[dn] = MFMA16(vfr, pb, o[dn]);
      }
    }
#pragma unroll
    for (int dn = 0; dn < 4; ++dn) vA[dn] += 64;
  }

  // normalize + store O[b][qrow][h*64 + d], d = dn*16 + lg*4 + t
  float inv = 1.f / lrow;
  unsigned short* Op = O + ((size_t)(b * 1024 + qrow)) * 1024 + h * 64;
#pragma unroll
  for (int dn = 0; dn < 4; ++dn) {
    u32x2 v2;
    v2[0] = packbf2(o[dn][0] * inv, o[dn][1] * inv);
    v2[1] = packbf2(o[dn][2] * inv, o[dn][3] * inv);
    *(u32x2*)(Op + dn * 16 + lg * 4) = v2;
  }
}

// ---------------------------------------------------------------------------
// Kernel 4: output projection GEMM, global_load_lds staging (proven round 5).
// grid (8, 128), block 256
// ---------------------------------------------------------------------------
__global__ __launch_bounds__(256) void out_gemm(
    const unsigned short* __restrict__ A, const unsigned short* __restrict__ Bt,
    float* __restrict__ C)
{
  const int bn = blockIdx.x * 128;
  const int bm = blockIdx.y * 128;
  const int tid = threadIdx.x;
  const int w = tid >> 6, l = tid & 63, l15 = l & 15, lg = l >> 4;
  const int wr = w >> 1, wc = w & 1;

  __shared__ alignas(16) unsigned short sA[128][32];
  __shared__ alignas(16) unsigned short sB[128][32];

  const int srow = w * 32 + (l >> 2);
  const int scol = (l & 3) * 8;
  const unsigned short* gA = A + (size_t)(bm + srow) * 1024 + scol;
  const unsigned short* gB = Bt + (size_t)(bn + srow) * 1024 + scol;
  unsigned short* lA = &sA[srow][scol];
  unsigned short* lB = &sB[srow][scol];

  f32x4 acc[4][4];
  const f32x4 zero = {0.f, 0.f, 0.f, 0.f};
#pragma unroll
  for (int i = 0; i < 4; ++i)
#pragma unroll
    for (int j = 0; j < 4; ++j) acc[i][j] = zero;

  for (int k0 = 0; k0 < 1024; k0 += 32) {
    __syncthreads();
#pragma unroll
    for (int p = 0; p < 2; ++p) {
      gload16(gA + (size_t)p * 16 * 1024 + k0, lA + p * 16 * 32);
      gload16(gB + (size_t)p * 16 * 1024 + k0, lB + p * 16 * 32);
    }
    __syncthreads();

    u16x8 af[4], bf[4];
#pragma unroll
    for (int m = 0; m < 4; ++m)
      af[m] = *(const u16x8*)&sA[wr * 64 + m * 16 + l15][lg * 8];
#pragma unroll
    for (int n = 0; n < 4; ++n)
      bf[n] = *(const u16x8*)&sB[wc * 64 + n * 16 + l15][lg * 8];
#pragma unroll
    for (int m = 0; m < 4; ++m)
#pragma unroll
      for (int n = 0; n < 4; ++n)
        acc[m][n] = MFMA16(af[m], bf[n], acc[m][n]);
  }

#pragma unroll
  for (int m = 0; m < 4; ++m) {
    int grow_b = bm + wr * 64 + m * 16 + lg * 4;
#pragma unroll
    for (int n = 0; n < 4; ++n) {
      int gcol = bn + wc * 64 + n * 16 + l15;
#pragma unroll
      for (int t = 0; t < 4; ++t)
        C[(size_t)(grow_b + t) * 1024 + gcol] = acc[m][n][t];
    }
  }
}

// ---------------------------------------------------------------------------
extern "C" void kernel_launch(void* const* d_in, const int* in_sizes, int n_in,
                              void* d_out, int out_size, void* d_ws, size_t ws_size,
                              hipStream_t stream) {
  const float* X  = (const float*)d_in[0];   // [16,1024,1024]
  const float* LL = (const float*)d_in[1];   // [1024,1024]
  const float* Wq = (const float*)d_in[2];
  const float* Wk = (const float*)d_in[3];
  const float* Wv = (const float*)d_in[4];
  const float* Wo = (const float*)d_in[5];
  const float* bt = (const float*)d_in[6];   // [16]
  float* out = (float*)d_out;

  unsigned short* ws = (unsigned short*)d_ws;
  const size_t QKV = (size_t)16 * 16 * 1024 * 64;   // 16M elems each
  unsigned short* Qb = ws;
  unsigned short* Kb = Qb + QKV;
  unsigned short* Vb = Kb + QKV;       // dead after vtrans; reused as Ob
  unsigned short* Vt = Vb + QKV;
  unsigned short* Wt = Vt + QKV;       // 4 x 1M elems
  unsigned short* Ob = Vb;             // alias: attn output
  unsigned short* Xbb = Vt;            // alias: Xb dead before vtrans writes Vt

  xconv<<<dim3(8192), 256, 0, stream>>>(X, Xbb);
  wtrans<<<dim3(32, 32, 4), dim3(32, 8), 0, stream>>>(Wq, Wk, Wv, Wo, Wt);
  qkv_gemm<<<dim3(24, 128), 256, 0, stream>>>(Xbb, Wt, Qb, Kb, Vb);
  vtrans<<<dim3(16, 256), 256, 0, stream>>>(Vb, Vt);
  attn<<<dim3(16, 16, 16), 256, 0, stream>>>(Qb, Kb, Vt, LL, bt, Ob);
  out_gemm<<<dim3(8, 128), 256, 0, stream>>>(Ob, Wt + 3 * 1024 * 1024, out);
}